// Round 1
// baseline (511.933 us; speedup 1.0000x reference)
//
#include <hip/hip_runtime.h>

#define N_NODES 50000
#define N_EDGES 1600000
#define IN_DIM 512
#define HID_DIM 128
#define OUT_DIM 16

// ---------------- sort edges by dst (counting sort) ----------------

__global__ void hist_kernel(const int* __restrict__ dst, int* __restrict__ counts) {
    int e = blockIdx.x * blockDim.x + threadIdx.x;
    if (e < N_EDGES) atomicAdd(&counts[dst[e]], 1);
}

__device__ inline int wave_incl_scan(int v) {
    #pragma unroll
    for (int off = 1; off < 64; off <<= 1) {
        int x = __shfl_up(v, off, 64);
        if ((threadIdx.x & 63) >= off) v += x;
    }
    return v;
}

// single-block exclusive scan over counts[N_NODES] -> row_ptr[N_NODES+1], copy to off_work
__global__ __launch_bounds__(1024) void scan_kernel(const int* __restrict__ counts,
                                                    int* __restrict__ row_ptr,
                                                    int* __restrict__ off_work) {
    __shared__ int wsum[16];
    __shared__ int s_carry;
    const int t = threadIdx.x;
    const int lane = t & 63, wid = t >> 6;
    if (t == 0) s_carry = 0;
    __syncthreads();
    for (int base = 0; base < N_NODES; base += 1024) {
        int i = base + t;
        int v = (i < N_NODES) ? counts[i] : 0;
        int incl = wave_incl_scan(v);
        if (lane == 63) wsum[wid] = incl;
        __syncthreads();                       // A: wsum per-wave totals visible
        int carry = s_carry;
        if (wid == 0) {
            int wv = (lane < 16) ? wsum[lane] : 0;
            int ws = wave_incl_scan(wv);
            if (lane < 16) wsum[lane] = ws;    // inclusive scan of wave totals
        }
        __syncthreads();                       // B
        int woff = (wid > 0) ? wsum[wid - 1] : 0;
        int total = wsum[15];
        int excl = carry + woff + incl - v;
        if (i < N_NODES) { row_ptr[i] = excl; off_work[i] = excl; }
        __syncthreads();                       // C: all reads of wsum/s_carry done
        if (t == 0) s_carry = carry + total;
        __syncthreads();                       // D
    }
    if (t == 0) row_ptr[N_NODES] = s_carry;
}

__global__ void scatter_kernel(const int* __restrict__ src, const int* __restrict__ dst,
                               const float* __restrict__ val, int* __restrict__ off_work,
                               int* __restrict__ s_src, float* __restrict__ s_val) {
    int e = blockIdx.x * blockDim.x + threadIdx.x;
    if (e < N_EDGES) {
        int p = atomicAdd(&off_work[dst[e]], 1);
        s_src[p] = src[e];
        s_val[p] = val[e];
    }
}

// ---------------- GEMM1: h0[N,128] = X[N,512] @ W1[512,128] (f32) ----------------

__global__ __launch_bounds__(256) void gemm1_kernel(const float* __restrict__ X,
                                                    const float* __restrict__ W,
                                                    float* __restrict__ C) {
    __shared__ float Xs[32][36];
    __shared__ float Ws[32][128];
    const int t = threadIdx.x;
    const int m0 = blockIdx.x * 32;
    const int r = t >> 5;   // 0..7 -> rows r*4..r*4+3
    const int c = t & 31;   // 0..31 -> cols c*4..c*4+3
    float acc[4][4];
    #pragma unroll
    for (int i = 0; i < 4; i++)
        #pragma unroll
        for (int j = 0; j < 4; j++) acc[i][j] = 0.f;

    for (int k0 = 0; k0 < IN_DIM; k0 += 32) {
        {   // X tile: 32 rows x 32 k, one float4 per thread
            int lr = t >> 3;
            int col = (t & 7) * 4;
            int row = m0 + lr;
            float4 v = make_float4(0.f, 0.f, 0.f, 0.f);
            if (row < N_NODES) v = *(const float4*)&X[(size_t)row * IN_DIM + k0 + col];
            Xs[lr][col + 0] = v.x; Xs[lr][col + 1] = v.y;
            Xs[lr][col + 2] = v.z; Xs[lr][col + 3] = v.w;
        }
        #pragma unroll
        for (int p = 0; p < 4; p++) {   // W tile: 32 rows x 128
            int row = p * 8 + (t >> 5);
            int col = (t & 31) * 4;
            float4 v = *(const float4*)&W[(size_t)(k0 + row) * HID_DIM + col];
            *(float4*)&Ws[row][col] = v;
        }
        __syncthreads();
        #pragma unroll
        for (int k = 0; k < 32; k++) {
            float4 wv = *(const float4*)&Ws[k][c * 4];
            #pragma unroll
            for (int i = 0; i < 4; i++) {
                float x = Xs[r * 4 + i][k];
                acc[i][0] += x * wv.x; acc[i][1] += x * wv.y;
                acc[i][2] += x * wv.z; acc[i][3] += x * wv.w;
            }
        }
        __syncthreads();
    }
    #pragma unroll
    for (int i = 0; i < 4; i++) {
        int row = m0 + r * 4 + i;
        if (row < N_NODES) {
            float4 v = make_float4(acc[i][0], acc[i][1], acc[i][2], acc[i][3]);
            *(float4*)&C[(size_t)row * HID_DIM + c * 4] = v;
        }
    }
}

// ---------------- SpMM1 + ReLU: h[n][:] = relu(sum_e val*h0[src][:]) ----------------

__global__ __launch_bounds__(128) void spmm1_relu_kernel(const float* __restrict__ h0,
                                                         const int* __restrict__ row_ptr,
                                                         const int* __restrict__ esrc,
                                                         const float* __restrict__ eval,
                                                         float* __restrict__ h) {
    __shared__ int s_src[64];
    __shared__ float s_val[64];
    const int n = blockIdx.x;
    const int d = threadIdx.x;
    const int s = row_ptr[n], e = row_ptr[n + 1];
    float acc = 0.f;
    for (int base = s; base < e; base += 64) {
        int cnt = min(64, e - base);
        if (d < 64) { if (d < cnt) s_src[d] = esrc[base + d]; }
        else        { if (d - 64 < cnt) s_val[d - 64] = eval[base + d - 64]; }
        __syncthreads();
        for (int i = 0; i < cnt; i++)
            acc += s_val[i] * h0[(size_t)s_src[i] * HID_DIM + d];
        __syncthreads();
    }
    h[(size_t)n * HID_DIM + d] = fmaxf(acc, 0.f);
}

// ---------------- GEMM2: h2[N,16] = h[N,128] @ W2[128,16] ----------------

__global__ __launch_bounds__(256) void gemm2_kernel(const float* __restrict__ H,
                                                    const float* __restrict__ W2,
                                                    float* __restrict__ C) {
    __shared__ float Hs[16][132];
    __shared__ float Ws[128][16];
    const int t = threadIdx.x;
    const int n0 = blockIdx.x * 16;
    #pragma unroll
    for (int p = 0; p < 2; p++) {   // W2: 2048 floats = 512 float4
        int idx = p * 256 + t;
        ((float4*)Ws)[idx] = ((const float4*)W2)[idx];
    }
    #pragma unroll
    for (int p = 0; p < 2; p++) {   // H tile: 16 x 128
        int idx = p * 256 + t;
        int row = idx >> 5, col = (idx & 31) * 4;
        int gr = n0 + row;
        float4 v = make_float4(0.f, 0.f, 0.f, 0.f);
        if (gr < N_NODES) v = *(const float4*)&H[(size_t)gr * HID_DIM + col];
        Hs[row][col + 0] = v.x; Hs[row][col + 1] = v.y;
        Hs[row][col + 2] = v.z; Hs[row][col + 3] = v.w;
    }
    __syncthreads();
    const int nl = t >> 4, j = t & 15;
    float acc = 0.f;
    #pragma unroll 8
    for (int k = 0; k < 128; k++) acc += Hs[nl][k] * Ws[k][j];
    int n = n0 + nl;
    if (n < N_NODES) C[(size_t)n * OUT_DIM + j] = acc;
}

// ---------------- SpMM2: out[n][:16] = sum_e val*h2[src][:16] ----------------

__global__ __launch_bounds__(128) void spmm2_kernel(const float* __restrict__ h2,
                                                    const int* __restrict__ row_ptr,
                                                    const int* __restrict__ esrc,
                                                    const float* __restrict__ eval,
                                                    float* __restrict__ out) {
    const int n = blockIdx.x * 8 + (threadIdx.x >> 4);
    const int d = threadIdx.x & 15;
    if (n >= N_NODES) return;
    const int s = row_ptr[n], e = row_ptr[n + 1];
    float acc = 0.f;
    for (int i = s; i < e; i++)
        acc += eval[i] * h2[(size_t)esrc[i] * OUT_DIM + d];
    out[(size_t)n * OUT_DIM + d] = acc;
}

// ---------------- launch ----------------

extern "C" void kernel_launch(void* const* d_in, const int* in_sizes, int n_in,
                              void* d_out, int out_size, void* d_ws, size_t ws_size,
                              hipStream_t stream) {
    const float* feature   = (const float*)d_in[0];
    const int*   edge_src  = (const int*)d_in[1];
    const int*   edge_dst  = (const int*)d_in[2];
    const float* edge_vals = (const float*)d_in[3];
    const float* W1        = (const float*)d_in[4];
    const float* W2        = (const float*)d_in[5];
    float* out = (float*)d_out;

    char* ws = (char*)d_ws;
    size_t off = 0;
    auto alloc = [&](size_t bytes) {
        void* p = ws + off;
        off += (bytes + 255) & ~(size_t)255;
        return p;
    };
    float* h0         = (float*)alloc((size_t)N_NODES * HID_DIM * 4);
    float* h          = (float*)alloc((size_t)N_NODES * HID_DIM * 4);
    float* h2         = (float*)alloc((size_t)N_NODES * OUT_DIM * 4);
    int*   counts     = (int*)alloc((size_t)N_NODES * 4);
    int*   row_ptr    = (int*)alloc((size_t)(N_NODES + 1) * 4);
    int*   off_work   = (int*)alloc((size_t)N_NODES * 4);
    int*   src_sorted = (int*)alloc((size_t)N_EDGES * 4);
    float* val_sorted = (float*)alloc((size_t)N_EDGES * 4);

    hipMemsetAsync(counts, 0, (size_t)N_NODES * 4, stream);
    hist_kernel<<<(N_EDGES + 255) / 256, 256, 0, stream>>>(edge_dst, counts);
    scan_kernel<<<1, 1024, 0, stream>>>(counts, row_ptr, off_work);
    scatter_kernel<<<(N_EDGES + 255) / 256, 256, 0, stream>>>(edge_src, edge_dst, edge_vals,
                                                              off_work, src_sorted, val_sorted);
    gemm1_kernel<<<(N_NODES + 31) / 32, 256, 0, stream>>>(feature, W1, h0);
    spmm1_relu_kernel<<<N_NODES, 128, 0, stream>>>(h0, row_ptr, src_sorted, val_sorted, h);
    gemm2_kernel<<<(N_NODES + 15) / 16, 256, 0, stream>>>(h, W2, h2);
    spmm2_kernel<<<(N_NODES + 7) / 8, 128, 0, stream>>>(h2, row_ptr, src_sorted, val_sorted, out);
}

// Round 2
// 469.074 us; speedup vs baseline: 1.0914x; 1.0914x over previous
//
#include <hip/hip_runtime.h>

#define N_NODES 50000
#define N_EDGES 1600000
#define IN_DIM 512
#define HID_DIM 128
#define OUT_DIM 16

// ---------------- CSR build: hist -> multiblock scan -> packed scatter ----------------

__global__ void hist_kernel(const int* __restrict__ dst, int* __restrict__ counts) {
    int e = blockIdx.x * blockDim.x + threadIdx.x;
    if (e < N_EDGES) atomicAdd(&counts[dst[e]], 1);
}

__device__ inline int wave_incl_scan(int v) {
    #pragma unroll
    for (int off = 1; off < 64; off <<= 1) {
        int x = __shfl_up(v, off, 64);
        if ((threadIdx.x & 63) >= off) v += x;
    }
    return v;
}

#define SCAN_ELEMS 2048  // per block: 256 threads x 8
#define SCAN_BLOCKS ((N_NODES + SCAN_ELEMS - 1) / SCAN_ELEMS)  // 25

__global__ __launch_bounds__(256) void scan_blocks_kernel(const int* __restrict__ counts,
                                                          int* __restrict__ excl,
                                                          int* __restrict__ blk_sums) {
    __shared__ int wsums[4];
    const int t = threadIdx.x;
    const int base = blockIdx.x * SCAN_ELEMS + t * 8;
    int v[8];
    int s = 0;
    #pragma unroll
    for (int i = 0; i < 8; i++) {
        int idx = base + i;
        v[i] = (idx < N_NODES) ? counts[idx] : 0;
        s += v[i];
    }
    int incl = wave_incl_scan(s);
    if ((t & 63) == 63) wsums[t >> 6] = incl;
    __syncthreads();
    int woff = 0;
    for (int w = 0; w < (t >> 6); w++) woff += wsums[w];
    int run = woff + incl - s;  // exclusive prefix for this thread's first element
    #pragma unroll
    for (int i = 0; i < 8; i++) {
        int idx = base + i;
        if (idx < N_NODES) excl[idx] = run;
        run += v[i];
    }
    if (t == 255) blk_sums[blockIdx.x] = woff + incl;
}

__global__ void scan_tops_kernel(int* __restrict__ blk_sums, int* __restrict__ row_ptr) {
    int t = threadIdx.x;  // 64 threads
    int v = (t < SCAN_BLOCKS) ? blk_sums[t] : 0;
    int incl = wave_incl_scan(v);
    if (t < SCAN_BLOCKS) blk_sums[t] = incl - v;  // exclusive
    if (t == 63) row_ptr[N_NODES] = incl;         // grand total
}

__global__ void add_offsets_kernel(const int* __restrict__ excl, const int* __restrict__ blk_sums,
                                   int* __restrict__ row_ptr, int* __restrict__ off_work) {
    int i = blockIdx.x * blockDim.x + threadIdx.x;
    if (i < N_NODES) {
        int v = excl[i] + blk_sums[i >> 11];  // 2048 = 1<<11
        row_ptr[i] = v;
        off_work[i] = v;
    }
}

__global__ void scatter_kernel(const int* __restrict__ src, const int* __restrict__ dst,
                               const float* __restrict__ val, int* __restrict__ off_work,
                               int2* __restrict__ pairs) {
    int e = blockIdx.x * blockDim.x + threadIdx.x;
    if (e < N_EDGES) {
        int p = atomicAdd(&off_work[dst[e]], 1);
        int2 pr;
        pr.x = src[e];
        pr.y = __float_as_int(val[e]);
        pairs[p] = pr;
    }
}

// ---------------- GEMM1: h0[N,128] = X[N,512] @ W1[512,128] (f32) ----------------
// 64x128 tile, 256 threads, 4x8 per-thread micro-tile, X staged transposed.

__global__ __launch_bounds__(256) void gemm1_kernel(const float* __restrict__ X,
                                                    const float* __restrict__ W,
                                                    float* __restrict__ C) {
    __shared__ float Xs[32][68];   // [k][m], pad 68 keeps float4 alignment (68*4=272=16*17)
    __shared__ float Ws[32][128];  // [k][n]
    const int t = threadIdx.x;
    const int m0 = blockIdx.x * 64;
    const int tr = t >> 4;   // 0..15 -> rows tr*4 .. tr*4+3
    const int tc = t & 15;   // 0..15 -> cols tc*4..+3 and 64+tc*4..+3
    float acc[4][8];
    #pragma unroll
    for (int i = 0; i < 4; i++)
        #pragma unroll
        for (int j = 0; j < 8; j++) acc[i][j] = 0.f;

    for (int k0 = 0; k0 < IN_DIM; k0 += 32) {
        // X tile: 64 rows x 32 k -> transposed into Xs[k][m]
        #pragma unroll
        for (int p = 0; p < 2; p++) {
            int idx = p * 256 + t;        // 0..511
            int lr  = idx >> 3;           // 0..63 row
            int kk  = (idx & 7) * 4;      // 0..28
            int row = m0 + lr;
            float4 v = make_float4(0.f, 0.f, 0.f, 0.f);
            if (row < N_NODES) v = *(const float4*)&X[(size_t)row * IN_DIM + k0 + kk];
            Xs[kk + 0][lr] = v.x; Xs[kk + 1][lr] = v.y;
            Xs[kk + 2][lr] = v.z; Xs[kk + 3][lr] = v.w;
        }
        // W tile: 32 rows x 128
        #pragma unroll
        for (int p = 0; p < 4; p++) {
            int idx = p * 256 + t;
            int row = idx >> 5, col = (idx & 31) * 4;
            *(float4*)&Ws[row][col] = *(const float4*)&W[(size_t)(k0 + row) * HID_DIM + col];
        }
        __syncthreads();
        #pragma unroll 8
        for (int k = 0; k < 32; k++) {
            float4 xv = *(const float4*)&Xs[k][tr * 4];
            float4 w0 = *(const float4*)&Ws[k][tc * 4];
            float4 w1 = *(const float4*)&Ws[k][64 + tc * 4];
            #pragma unroll
            for (int i = 0; i < 4; i++) {
                float x = (i == 0) ? xv.x : (i == 1) ? xv.y : (i == 2) ? xv.z : xv.w;
                acc[i][0] += x * w0.x; acc[i][1] += x * w0.y;
                acc[i][2] += x * w0.z; acc[i][3] += x * w0.w;
                acc[i][4] += x * w1.x; acc[i][5] += x * w1.y;
                acc[i][6] += x * w1.z; acc[i][7] += x * w1.w;
            }
        }
        __syncthreads();
    }
    #pragma unroll
    for (int i = 0; i < 4; i++) {
        int row = m0 + tr * 4 + i;
        if (row < N_NODES) {
            float4 a = make_float4(acc[i][0], acc[i][1], acc[i][2], acc[i][3]);
            float4 b = make_float4(acc[i][4], acc[i][5], acc[i][6], acc[i][7]);
            *(float4*)&C[(size_t)row * HID_DIM + tc * 4] = a;
            *(float4*)&C[(size_t)row * HID_DIM + 64 + tc * 4] = b;
        }
    }
}

// ---------------- SpMM1 + ReLU ----------------

__global__ __launch_bounds__(128) void spmm1_relu_kernel(const float* __restrict__ h0,
                                                         const int* __restrict__ row_ptr,
                                                         const int2* __restrict__ pairs,
                                                         float* __restrict__ h) {
    __shared__ int s_src[64];
    __shared__ float s_val[64];
    const int n = blockIdx.x;
    const int d = threadIdx.x;
    const int s = row_ptr[n], e = row_ptr[n + 1];
    float acc = 0.f;
    for (int base = s; base < e; base += 64) {
        int cnt = min(64, e - base);
        if (d < 64 && d < cnt) {
            int2 pr = pairs[base + d];
            s_src[d] = pr.x;
            s_val[d] = __int_as_float(pr.y);
        }
        __syncthreads();
        for (int i = 0; i < cnt; i++)
            acc += s_val[i] * h0[(size_t)s_src[i] * HID_DIM + d];
        __syncthreads();
    }
    h[(size_t)n * HID_DIM + d] = fmaxf(acc, 0.f);
}

// ---------------- GEMM2: h2[N,16] = h[N,128] @ W2[128,16] ----------------

__global__ __launch_bounds__(256) void gemm2_kernel(const float* __restrict__ H,
                                                    const float* __restrict__ W2,
                                                    float* __restrict__ C) {
    __shared__ float Hs[16][132];
    __shared__ float Ws[128][16];
    const int t = threadIdx.x;
    const int n0 = blockIdx.x * 16;
    #pragma unroll
    for (int p = 0; p < 2; p++) {
        int idx = p * 256 + t;
        ((float4*)Ws)[idx] = ((const float4*)W2)[idx];
    }
    #pragma unroll
    for (int p = 0; p < 2; p++) {
        int idx = p * 256 + t;
        int row = idx >> 5, col = (idx & 31) * 4;
        int gr = n0 + row;
        float4 v = make_float4(0.f, 0.f, 0.f, 0.f);
        if (gr < N_NODES) v = *(const float4*)&H[(size_t)gr * HID_DIM + col];
        Hs[row][col + 0] = v.x; Hs[row][col + 1] = v.y;
        Hs[row][col + 2] = v.z; Hs[row][col + 3] = v.w;
    }
    __syncthreads();
    const int nl = t >> 4, j = t & 15;
    float acc = 0.f;
    #pragma unroll 8
    for (int k = 0; k < 128; k++) acc += Hs[nl][k] * Ws[k][j];
    int n = n0 + nl;
    if (n < N_NODES) C[(size_t)n * OUT_DIM + j] = acc;
}

// ---------------- SpMM2 ----------------

__global__ __launch_bounds__(128) void spmm2_kernel(const float* __restrict__ h2,
                                                    const int* __restrict__ row_ptr,
                                                    const int2* __restrict__ pairs,
                                                    float* __restrict__ out) {
    const int n = blockIdx.x * 8 + (threadIdx.x >> 4);
    const int d = threadIdx.x & 15;
    if (n >= N_NODES) return;
    const int s = row_ptr[n], e = row_ptr[n + 1];
    float acc = 0.f;
    for (int i = s; i < e; i++) {
        int2 pr = pairs[i];
        acc += __int_as_float(pr.y) * h2[(size_t)pr.x * OUT_DIM + d];
    }
    out[(size_t)n * OUT_DIM + d] = acc;
}

// ---------------- launch ----------------

extern "C" void kernel_launch(void* const* d_in, const int* in_sizes, int n_in,
                              void* d_out, int out_size, void* d_ws, size_t ws_size,
                              hipStream_t stream) {
    const float* feature   = (const float*)d_in[0];
    const int*   edge_src  = (const int*)d_in[1];
    const int*   edge_dst  = (const int*)d_in[2];
    const float* edge_vals = (const float*)d_in[3];
    const float* W1        = (const float*)d_in[4];
    const float* W2        = (const float*)d_in[5];
    float* out = (float*)d_out;

    char* ws = (char*)d_ws;
    size_t off = 0;
    auto alloc = [&](size_t bytes) {
        void* p = ws + off;
        off += (bytes + 255) & ~(size_t)255;
        return p;
    };
    float* h0       = (float*)alloc((size_t)N_NODES * HID_DIM * 4);
    float* h        = (float*)alloc((size_t)N_NODES * HID_DIM * 4);
    float* h2       = (float*)alloc((size_t)N_NODES * OUT_DIM * 4);
    int*   counts   = (int*)alloc((size_t)N_NODES * 4);
    int*   row_ptr  = (int*)alloc((size_t)(N_NODES + 1) * 4);
    int*   off_work = (int*)alloc((size_t)N_NODES * 4);
    int*   excl_tmp = (int*)alloc((size_t)N_NODES * 4);
    int*   blk_sums = (int*)alloc(64 * 4);
    int2*  pairs    = (int2*)alloc((size_t)N_EDGES * 8);

    hipMemsetAsync(counts, 0, (size_t)N_NODES * 4, stream);
    hist_kernel<<<(N_EDGES + 255) / 256, 256, 0, stream>>>(edge_dst, counts);
    scan_blocks_kernel<<<SCAN_BLOCKS, 256, 0, stream>>>(counts, excl_tmp, blk_sums);
    scan_tops_kernel<<<1, 64, 0, stream>>>(blk_sums, row_ptr);
    add_offsets_kernel<<<(N_NODES + 255) / 256, 256, 0, stream>>>(excl_tmp, blk_sums,
                                                                  row_ptr, off_work);
    scatter_kernel<<<(N_EDGES + 255) / 256, 256, 0, stream>>>(edge_src, edge_dst, edge_vals,
                                                              off_work, pairs);
    gemm1_kernel<<<(N_NODES + 63) / 64, 256, 0, stream>>>(feature, W1, h0);
    spmm1_relu_kernel<<<N_NODES, 128, 0, stream>>>(h0, row_ptr, pairs, h);
    gemm2_kernel<<<(N_NODES + 15) / 16, 256, 0, stream>>>(h, W2, h2);
    spmm2_kernel<<<(N_NODES + 7) / 8, 128, 0, stream>>>(h2, row_ptr, pairs, out);
}

// Round 3
// 365.166 us; speedup vs baseline: 1.4019x; 1.2846x over previous
//
#include <hip/hip_runtime.h>

#define N_NODES 50000
#define N_EDGES 1600000
#define IN_DIM 512
#define HID_DIM 128
#define OUT_DIM 16

typedef __attribute__((ext_vector_type(8))) __bf16 bf16x8;
typedef __attribute__((ext_vector_type(8))) unsigned short ushort8;
typedef __attribute__((ext_vector_type(4))) float f32x4;

static __device__ __forceinline__ unsigned short f2bf(float x) {
    unsigned int u = __float_as_uint(x);
    u += 0x7FFFu + ((u >> 16) & 1u);   // round-to-nearest-even
    return (unsigned short)(u >> 16);
}
static __device__ __forceinline__ float bf2f(unsigned short v) {
    return __uint_as_float(((unsigned int)v) << 16);
}

// ---------------- CSR build: hist -> multiblock scan -> packed scatter ----------------

__global__ void hist_kernel(const int* __restrict__ dst, int* __restrict__ counts) {
    int e = blockIdx.x * blockDim.x + threadIdx.x;
    if (e < N_EDGES) atomicAdd(&counts[dst[e]], 1);
}

__device__ inline int wave_incl_scan(int v) {
    #pragma unroll
    for (int off = 1; off < 64; off <<= 1) {
        int x = __shfl_up(v, off, 64);
        if ((threadIdx.x & 63) >= off) v += x;
    }
    return v;
}

#define SCAN_ELEMS 2048
#define SCAN_BLOCKS ((N_NODES + SCAN_ELEMS - 1) / SCAN_ELEMS)  // 25

__global__ __launch_bounds__(256) void scan_blocks_kernel(const int* __restrict__ counts,
                                                          int* __restrict__ excl,
                                                          int* __restrict__ blk_sums) {
    __shared__ int wsums[4];
    const int t = threadIdx.x;
    const int base = blockIdx.x * SCAN_ELEMS + t * 8;
    int v[8];
    int s = 0;
    #pragma unroll
    for (int i = 0; i < 8; i++) {
        int idx = base + i;
        v[i] = (idx < N_NODES) ? counts[idx] : 0;
        s += v[i];
    }
    int incl = wave_incl_scan(s);
    if ((t & 63) == 63) wsums[t >> 6] = incl;
    __syncthreads();
    int woff = 0;
    for (int w = 0; w < (t >> 6); w++) woff += wsums[w];
    int run = woff + incl - s;
    #pragma unroll
    for (int i = 0; i < 8; i++) {
        int idx = base + i;
        if (idx < N_NODES) excl[idx] = run;
        run += v[i];
    }
    if (t == 255) blk_sums[blockIdx.x] = woff + incl;
}

__global__ void scan_tops_kernel(int* __restrict__ blk_sums, int* __restrict__ row_ptr) {
    int t = threadIdx.x;
    int v = (t < SCAN_BLOCKS) ? blk_sums[t] : 0;
    int incl = wave_incl_scan(v);
    if (t < SCAN_BLOCKS) blk_sums[t] = incl - v;
    if (t == 63) row_ptr[N_NODES] = incl;
}

__global__ void add_offsets_kernel(const int* __restrict__ excl, const int* __restrict__ blk_sums,
                                   int* __restrict__ row_ptr, int* __restrict__ off_work) {
    int i = blockIdx.x * blockDim.x + threadIdx.x;
    if (i < N_NODES) {
        int v = excl[i] + blk_sums[i >> 11];
        row_ptr[i] = v;
        off_work[i] = v;
    }
}

__global__ void scatter_kernel(const int* __restrict__ src, const int* __restrict__ dst,
                               const float* __restrict__ val, int* __restrict__ off_work,
                               int2* __restrict__ pairs) {
    int e = blockIdx.x * blockDim.x + threadIdx.x;
    if (e < N_EDGES) {
        int p = atomicAdd(&off_work[dst[e]], 1);
        int2 pr;
        pr.x = src[e];
        pr.y = __float_as_int(val[e]);
        pairs[p] = pr;
    }
}

// ---------------- prep: Wt[col][k] = bf16(W1[k][col]) ----------------

__global__ void prep_w1_kernel(const float* __restrict__ W1, unsigned short* __restrict__ Wt) {
    int i = blockIdx.x * 256 + threadIdx.x;
    if (i < IN_DIM * HID_DIM) {
        int k = i >> 7, col = i & 127;
        Wt[(size_t)col * IN_DIM + k] = f2bf(W1[i]);
    }
}

// ---------------- GEMM1 (bf16 MFMA, zero-LDS): h0[N,128] = bf16(X @ W1) ----------------
// Block: 256 thr = 4 waves (2x2). Wave tile 64x64 = 4x4 of 16x16x32 MFMA.
// A-frags read f32 from global (rows block-private), cvt in regs.
// B-frags read bf16 from L2-resident Wt (one dwordx4 each).

__global__ __launch_bounds__(256) void gemm1_kernel(const float* __restrict__ X,
                                                    const unsigned short* __restrict__ Wt,
                                                    unsigned short* __restrict__ h0) {
    const int t = threadIdx.x;
    const int lane = t & 63;
    const int wave = t >> 6;
    const int wr = wave >> 1, wc = wave & 1;
    const int c = lane & 15, g = lane >> 4;
    const int m0 = blockIdx.x * 128 + wr * 64;

    f32x4 acc[4][4];
    #pragma unroll
    for (int mt = 0; mt < 4; mt++)
        #pragma unroll
        for (int nt = 0; nt < 4; nt++) acc[mt][nt] = (f32x4){0.f, 0.f, 0.f, 0.f};

    const float* aptr[4];
    #pragma unroll
    for (int mt = 0; mt < 4; mt++) {
        int r = m0 + mt * 16 + c;
        r = (r < N_NODES) ? r : (N_NODES - 1);   // clamp; stores guarded later
        aptr[mt] = X + (size_t)r * IN_DIM + g * 8;
    }
    const unsigned short* bptr[4];
    #pragma unroll
    for (int nt = 0; nt < 4; nt++) {
        int col = wc * 64 + nt * 16 + c;
        bptr[nt] = Wt + (size_t)col * IN_DIM + g * 8;
    }

    for (int k0 = 0; k0 < IN_DIM; k0 += 32) {
        bf16x8 bfrag[4];
        #pragma unroll
        for (int nt = 0; nt < 4; nt++)
            bfrag[nt] = *(const bf16x8*)(bptr[nt] + k0);
        #pragma unroll
        for (int mt = 0; mt < 4; mt++) {
            float4 a0 = *(const float4*)(aptr[mt] + k0);
            float4 a1 = *(const float4*)(aptr[mt] + k0 + 4);
            ushort8 af;
            af[0] = f2bf(a0.x); af[1] = f2bf(a0.y); af[2] = f2bf(a0.z); af[3] = f2bf(a0.w);
            af[4] = f2bf(a1.x); af[5] = f2bf(a1.y); af[6] = f2bf(a1.z); af[7] = f2bf(a1.w);
            bf16x8 afrag = __builtin_bit_cast(bf16x8, af);
            #pragma unroll
            for (int nt = 0; nt < 4; nt++)
                acc[mt][nt] = __builtin_amdgcn_mfma_f32_16x16x32_bf16(afrag, bfrag[nt],
                                                                      acc[mt][nt], 0, 0, 0);
        }
    }

    // C/D layout: col = lane&15, row_in_tile = (lane>>4)*4 + reg
    #pragma unroll
    for (int mt = 0; mt < 4; mt++) {
        #pragma unroll
        for (int r = 0; r < 4; r++) {
            int row = m0 + mt * 16 + g * 4 + r;
            if (row < N_NODES) {
                #pragma unroll
                for (int nt = 0; nt < 4; nt++) {
                    int col = wc * 64 + nt * 16 + c;
                    h0[(size_t)row * HID_DIM + col] = f2bf(acc[mt][nt][r]);
                }
            }
        }
    }
}

// ---------------- SpMM1 + ReLU (bf16 h0 gather) ----------------

__global__ __launch_bounds__(128) void spmm1_relu_kernel(const unsigned short* __restrict__ h0,
                                                         const int* __restrict__ row_ptr,
                                                         const int2* __restrict__ pairs,
                                                         float* __restrict__ h) {
    __shared__ int s_src[64];
    __shared__ float s_val[64];
    const int n = blockIdx.x;
    const int d = threadIdx.x;
    const int s = row_ptr[n], e = row_ptr[n + 1];
    float acc = 0.f;
    for (int base = s; base < e; base += 64) {
        int cnt = min(64, e - base);
        if (d < 64 && d < cnt) {
            int2 pr = pairs[base + d];
            s_src[d] = pr.x;
            s_val[d] = __int_as_float(pr.y);
        }
        __syncthreads();
        for (int i = 0; i < cnt; i++)
            acc += s_val[i] * bf2f(h0[(size_t)s_src[i] * HID_DIM + d]);
        __syncthreads();
    }
    h[(size_t)n * HID_DIM + d] = fmaxf(acc, 0.f);
}

// ---------------- GEMM2: h2[N,16] = h[N,128] @ W2[128,16] ----------------

__global__ __launch_bounds__(256) void gemm2_kernel(const float* __restrict__ H,
                                                    const float* __restrict__ W2,
                                                    float* __restrict__ C) {
    __shared__ float Hs[16][132];
    __shared__ float Ws[128][16];
    const int t = threadIdx.x;
    const int n0 = blockIdx.x * 16;
    #pragma unroll
    for (int p = 0; p < 2; p++) {
        int idx = p * 256 + t;
        ((float4*)Ws)[idx] = ((const float4*)W2)[idx];
    }
    #pragma unroll
    for (int p = 0; p < 2; p++) {
        int idx = p * 256 + t;
        int row = idx >> 5, col = (idx & 31) * 4;
        int gr = n0 + row;
        float4 v = make_float4(0.f, 0.f, 0.f, 0.f);
        if (gr < N_NODES) v = *(const float4*)&H[(size_t)gr * HID_DIM + col];
        Hs[row][col + 0] = v.x; Hs[row][col + 1] = v.y;
        Hs[row][col + 2] = v.z; Hs[row][col + 3] = v.w;
    }
    __syncthreads();
    const int nl = t >> 4, j = t & 15;
    float acc = 0.f;
    #pragma unroll 8
    for (int k = 0; k < 128; k++) acc += Hs[nl][k] * Ws[k][j];
    int n = n0 + nl;
    if (n < N_NODES) C[(size_t)n * OUT_DIM + j] = acc;
}

// ---------------- SpMM2 ----------------

__global__ __launch_bounds__(128) void spmm2_kernel(const float* __restrict__ h2,
                                                    const int* __restrict__ row_ptr,
                                                    const int2* __restrict__ pairs,
                                                    float* __restrict__ out) {
    const int n = blockIdx.x * 8 + (threadIdx.x >> 4);
    const int d = threadIdx.x & 15;
    if (n >= N_NODES) return;
    const int s = row_ptr[n], e = row_ptr[n + 1];
    float acc = 0.f;
    for (int i = s; i < e; i++) {
        int2 pr = pairs[i];
        acc += __int_as_float(pr.y) * h2[(size_t)pr.x * OUT_DIM + d];
    }
    out[(size_t)n * OUT_DIM + d] = acc;
}

// ---------------- launch ----------------

extern "C" void kernel_launch(void* const* d_in, const int* in_sizes, int n_in,
                              void* d_out, int out_size, void* d_ws, size_t ws_size,
                              hipStream_t stream) {
    const float* feature   = (const float*)d_in[0];
    const int*   edge_src  = (const int*)d_in[1];
    const int*   edge_dst  = (const int*)d_in[2];
    const float* edge_vals = (const float*)d_in[3];
    const float* W1        = (const float*)d_in[4];
    const float* W2        = (const float*)d_in[5];
    float* out = (float*)d_out;

    char* ws = (char*)d_ws;
    size_t off = 0;
    auto alloc = [&](size_t bytes) {
        void* p = ws + off;
        off += (bytes + 255) & ~(size_t)255;
        return p;
    };
    unsigned short* h0    = (unsigned short*)alloc((size_t)N_NODES * HID_DIM * 2);
    unsigned short* Wt    = (unsigned short*)alloc((size_t)IN_DIM * HID_DIM * 2);
    float* h              = (float*)alloc((size_t)N_NODES * HID_DIM * 4);
    float* h2             = (float*)alloc((size_t)N_NODES * OUT_DIM * 4);
    int*   counts         = (int*)alloc((size_t)N_NODES * 4);
    int*   row_ptr        = (int*)alloc((size_t)(N_NODES + 1) * 4);
    int*   off_work       = (int*)alloc((size_t)N_NODES * 4);
    int*   excl_tmp       = (int*)alloc((size_t)N_NODES * 4);
    int*   blk_sums       = (int*)alloc(64 * 4);
    int2*  pairs          = (int2*)alloc((size_t)N_EDGES * 8);

    hipMemsetAsync(counts, 0, (size_t)N_NODES * 4, stream);
    hist_kernel<<<(N_EDGES + 255) / 256, 256, 0, stream>>>(edge_dst, counts);
    scan_blocks_kernel<<<SCAN_BLOCKS, 256, 0, stream>>>(counts, excl_tmp, blk_sums);
    scan_tops_kernel<<<1, 64, 0, stream>>>(blk_sums, row_ptr);
    add_offsets_kernel<<<(N_NODES + 255) / 256, 256, 0, stream>>>(excl_tmp, blk_sums,
                                                                  row_ptr, off_work);
    scatter_kernel<<<(N_EDGES + 255) / 256, 256, 0, stream>>>(edge_src, edge_dst, edge_vals,
                                                              off_work, pairs);
    prep_w1_kernel<<<(IN_DIM * HID_DIM + 255) / 256, 256, 0, stream>>>(W1, Wt);
    gemm1_kernel<<<(N_NODES + 127) / 128, 256, 0, stream>>>(feature, Wt, h0);
    spmm1_relu_kernel<<<N_NODES, 128, 0, stream>>>(h0, row_ptr, pairs, h);
    gemm2_kernel<<<(N_NODES + 15) / 16, 256, 0, stream>>>(h, W2, h2);
    spmm2_kernel<<<(N_NODES + 7) / 8, 128, 0, stream>>>(h2, row_ptr, pairs, out);
}